// Round 1
// baseline (1104.600 us; speedup 1.0000x reference)
//
#include <hip/hip_runtime.h>
#include <hip/hip_bf16.h>
#include <stdint.h>

// Problem constants (from setup_inputs): E=8, T=2048, D=2048, I=1024
constexpr int E_ = 8, T_ = 2048, D_ = 2048, I_ = 1024;
#define EPS_ 1e-6f
#define QMAX_ 127.0f

typedef int v4i __attribute__((ext_vector_type(4)));

// ---------------------------------------------------------------------------
// Stage-A column abs-max: partial[(e*16+rc)*cols + col] = max over 128 rows
// grid: (cols/256, 16, E), block 256
// ---------------------------------------------------------------------------
__global__ __launch_bounds__(256) void colmax_partial(
    const float* __restrict__ src, float* __restrict__ partial,
    int rows_pc, int cols) {
  int e = blockIdx.z, rc = blockIdx.y;
  int col = blockIdx.x * 256 + threadIdx.x;
  const float* p = src + (size_t)e * gridDim.y * rows_pc * cols +
                   (size_t)rc * rows_pc * cols + col;
  float m = 0.f;
  for (int r = 0; r < rows_pc; ++r) m = fmaxf(m, fabsf(p[(size_t)r * cols]));
  partial[((size_t)e * gridDim.y + rc) * cols + col] = m;
}

// ---------------------------------------------------------------------------
// s = max(sqrt(max(ax,EPS)/max(aw,EPS)), EPS), reducing 16 partials each
// grid: (cols/256, E)
// ---------------------------------------------------------------------------
__global__ __launch_bounds__(256) void compute_s(
    const float* __restrict__ px, const float* __restrict__ pw,
    float* __restrict__ s, int cols) {
  int e = blockIdx.y;
  int c = blockIdx.x * 256 + threadIdx.x;
  float ax = 0.f, aw = 0.f;
  for (int k = 0; k < 16; ++k) {
    ax = fmaxf(ax, px[((size_t)e * 16 + k) * cols + c]);
    aw = fmaxf(aw, pw[((size_t)e * 16 + k) * cols + c]);
  }
  float sv = sqrtf(fmaxf(ax, EPS_) / fmaxf(aw, EPS_));
  s[(size_t)e * cols + c] = fmaxf(sv, EPS_);
}

// ---------------------------------------------------------------------------
// Per-row quantize: v = src*s (MUL, weights) or src/s (acts);
// scale = max(rowmax|v|,EPS)/127; q = clip(rint(v/scale),-127,127)
// grid: (rows, E), block 256. rscale[e*rows + r] = scale.
// ---------------------------------------------------------------------------
template <bool MUL, int COLS>
__global__ __launch_bounds__(256) void quant_rows(
    const float* __restrict__ src, const float* __restrict__ s,
    int8_t* __restrict__ q, float* __restrict__ rscale) {
  int e = blockIdx.y, r = blockIdx.x;
  const float* row = src + ((size_t)e * gridDim.x + r) * COLS;
  const float* sv = s + (size_t)e * COLS;
  constexpr int NIT = COLS / 256;
  float vv[NIT];
  float m = 0.f;
  for (int i = 0; i < NIT; ++i) {
    int c = i * 256 + threadIdx.x;
    float v = MUL ? row[c] * sv[c] : row[c] / sv[c];
    vv[i] = v;
    m = fmaxf(m, fabsf(v));
  }
  __shared__ float red[256];
  red[threadIdx.x] = m;
  __syncthreads();
  for (int st = 128; st > 0; st >>= 1) {
    if (threadIdx.x < st) red[threadIdx.x] = fmaxf(red[threadIdx.x], red[threadIdx.x + st]);
    __syncthreads();
  }
  float scale = fmaxf(red[0], EPS_) / QMAX_;
  int8_t* qrow = q + ((size_t)e * gridDim.x + r) * COLS;
  for (int i = 0; i < NIT; ++i) {
    int c = i * 256 + threadIdx.x;
    float qv = rintf(vv[i] / scale);       // round-half-even, same as jnp.round
    qv = fminf(fmaxf(qv, -QMAX_), QMAX_);
    qrow[c] = (int8_t)qv;
  }
  if (threadIdx.x == 0) rscale[(size_t)e * gridDim.x + r] = scale;
}

// ---------------------------------------------------------------------------
// int8 GEMM: C[m,n] = sum_k A[m,k]*B[n,k], dequant by asc[m]*bsc[n].
// B always has 2048 rows per expert. FUSE: compute gate (rows n0..) and up
// (rows 1024+n0..) tiles, apply SwiGLU, write a[T,I]. Else write out[T,NOUT].
// BM=128, BN=64, BK=64. block 256 (4 waves, 2x2), grid (NOUT/64, T/128, E).
// v_mfma_i32_16x16x32_i8: A frag = 8 int8 (i64) A[m=lane&15][k=quad*8+j];
// C/D: col=lane&15, row=quad*4+reg (m89-verified mapping, dtype-independent).
// ---------------------------------------------------------------------------
template <bool FUSE, int K, int NOUT>
__global__ __launch_bounds__(256) void gemm_i8(
    const int8_t* __restrict__ Aq, const int8_t* __restrict__ Bq,
    const float* __restrict__ asc, const float* __restrict__ bsc,
    float* __restrict__ outp) {
  constexpr int BM = 128, BN = 64, BK = 64;
  int e = blockIdx.z;
  int n0 = blockIdx.x * BN, m0 = blockIdx.y * BM;
  const int8_t* Ae = Aq + (size_t)e * T_ * K;
  const int8_t* Be = Bq + (size_t)e * 2048 * K;
  __shared__ int8_t sA[BM * BK];
  __shared__ int8_t sB[FUSE ? 2 : 1][BN * BK];
  int tid = threadIdx.x;
  int lane = tid & 63, wv = tid >> 6;
  int l16 = lane & 15, quad = lane >> 4;
  int wm = wv & 1, wn = wv >> 1;

  v4i accg[4][2], accu[4][2];
  for (int mt = 0; mt < 4; ++mt)
    for (int nt = 0; nt < 2; ++nt) {
      accg[mt][nt] = (v4i){0, 0, 0, 0};
      accu[mt][nt] = (v4i){0, 0, 0, 0};
    }

  for (int k0 = 0; k0 < K; k0 += BK) {
    // stage A tile (128x64 int8, 2 passes of 256x16B)
    for (int p = 0; p < 2; ++p) {
      int idx = p * 256 + tid;
      int row = idx >> 2, col = (idx & 3) << 4;
      *(int4*)(sA + row * BK + col) =
          *(const int4*)(Ae + (size_t)(m0 + row) * K + k0 + col);
    }
    // stage B tile(s) (64x64 int8 each, 1 pass)
    {
      int row = tid >> 2, col = (tid & 3) << 4;
      *(int4*)(&sB[0][row * BK + col]) =
          *(const int4*)(Be + (size_t)(n0 + row) * K + k0 + col);
      if (FUSE)
        *(int4*)(&sB[1][row * BK + col]) =
            *(const int4*)(Be + (size_t)(I_ + n0 + row) * K + k0 + col);
    }
    __syncthreads();
    for (int kk = 0; kk < BK; kk += 32) {
      long af[4];
      for (int mt = 0; mt < 4; ++mt)
        af[mt] = *(const long*)(sA + (wm * 64 + mt * 16 + l16) * BK + kk + quad * 8);
      long bf0[2], bf1[2];
      for (int nt = 0; nt < 2; ++nt) {
        int brow = wn * 32 + nt * 16 + l16;
        bf0[nt] = *(const long*)(&sB[0][brow * BK + kk + quad * 8]);
        if (FUSE) bf1[nt] = *(const long*)(&sB[1][brow * BK + kk + quad * 8]);
      }
      for (int mt = 0; mt < 4; ++mt)
        for (int nt = 0; nt < 2; ++nt) {
          accg[mt][nt] = __builtin_amdgcn_mfma_i32_16x16x32_i8(
              af[mt], bf0[nt], accg[mt][nt], 0, 0, 0);
          if (FUSE)
            accu[mt][nt] = __builtin_amdgcn_mfma_i32_16x16x32_i8(
                af[mt], bf1[nt], accu[mt][nt], 0, 0, 0);
        }
    }
    __syncthreads();
  }

  const float* ascE = asc + (size_t)e * T_;
  const float* bscE = bsc + (size_t)e * 2048;
  for (int mt = 0; mt < 4; ++mt)
    for (int nt = 0; nt < 2; ++nt)
      for (int r2 = 0; r2 < 4; ++r2) {
        int grow = m0 + wm * 64 + mt * 16 + quad * 4 + r2;
        int gcol = n0 + wn * 32 + nt * 16 + l16;
        float as = ascE[grow];
        if (FUSE) {
          float g = (float)accg[mt][nt][r2] * as * bscE[gcol];
          float u = (float)accu[mt][nt][r2] * as * bscE[I_ + gcol];
          float sg = g / (1.0f + expf(-g));  // silu
          outp[(size_t)e * T_ * NOUT + (size_t)grow * NOUT + gcol] = sg * u;
        } else {
          outp[(size_t)e * T_ * NOUT + (size_t)grow * NOUT + gcol] =
              (float)accg[mt][nt][r2] * as * bscE[gcol];
        }
      }
}

// ---------------------------------------------------------------------------
extern "C" void kernel_launch(void* const* d_in, const int* in_sizes, int n_in,
                              void* d_out, int out_size, void* d_ws, size_t ws_size,
                              hipStream_t stream) {
  const float* x   = (const float*)d_in[0];   // [E,T,D]
  const float* guw = (const float*)d_in[1];   // [E,2I,D]
  const float* dw  = (const float*)d_in[2];   // [E,D,I]
  float* out = (float*)d_out;                 // [E,T,D] fp32

  char* ws = (char*)d_ws;
  size_t off = 0;
  auto alloc = [&](size_t bytes) { char* p = ws + off; off += bytes; return p; };
  int8_t* xq   = (int8_t*)alloc((size_t)E_ * T_ * D_);        // 32 MB
  int8_t* wq1  = (int8_t*)alloc((size_t)E_ * 2 * I_ * D_);    // 32 MB
  int8_t* aq   = (int8_t*)alloc((size_t)E_ * T_ * I_);        // 16 MB
  int8_t* dwq  = (int8_t*)alloc((size_t)E_ * D_ * I_);        // 16 MB
  float*  a    = (float*)alloc((size_t)E_ * T_ * I_ * 4);     // 64 MB
  float*  px   = (float*)alloc((size_t)E_ * 16 * D_ * 4);
  float*  pw   = (float*)alloc((size_t)E_ * 16 * D_ * 4);
  float*  pdw  = (float*)alloc((size_t)E_ * 16 * I_ * 4);
  float*  pa   = (float*)alloc((size_t)E_ * 16 * I_ * 4);
  float*  s1   = (float*)alloc((size_t)E_ * D_ * 4);
  float*  s2   = (float*)alloc((size_t)E_ * I_ * 4);
  float*  xsc  = (float*)alloc((size_t)E_ * T_ * 4);
  float*  wsc1 = (float*)alloc((size_t)E_ * 2 * I_ * 4);
  float*  asc  = (float*)alloc((size_t)E_ * T_ * 4);
  float*  dwsc = (float*)alloc((size_t)E_ * D_ * 4);

  dim3 b(256);
  // Linear 1 smoothing scales
  colmax_partial<<<dim3(D_ / 256, 16, E_), b, 0, stream>>>(x, px, 128, D_);
  colmax_partial<<<dim3(D_ / 256, 16, E_), b, 0, stream>>>(guw, pw, 128, D_);
  colmax_partial<<<dim3(I_ / 256, 16, E_), b, 0, stream>>>(dw, pdw, 128, I_);
  compute_s<<<dim3(D_ / 256, E_), b, 0, stream>>>(px, pw, s1, D_);
  // Quantize x (div by s) and guw (mul by s)
  quant_rows<false, D_><<<dim3(T_, E_), b, 0, stream>>>(x, s1, xq, xsc);
  quant_rows<true, D_><<<dim3(2 * I_, E_), b, 0, stream>>>(guw, s1, wq1, wsc1);
  // GEMM1 + SwiGLU -> a [E,T,I]
  gemm_i8<true, D_, I_><<<dim3(I_ / 64, T_ / 128, E_), b, 0, stream>>>(
      xq, wq1, xsc, wsc1, a);
  // Linear 2 smoothing scales
  colmax_partial<<<dim3(I_ / 256, 16, E_), b, 0, stream>>>(a, pa, 128, I_);
  compute_s<<<dim3(I_ / 256, E_), b, 0, stream>>>(pa, pdw, s2, I_);
  quant_rows<false, I_><<<dim3(T_, E_), b, 0, stream>>>(a, s2, aq, asc);
  quant_rows<true, I_><<<dim3(D_, E_), b, 0, stream>>>(dw, s2, dwq, dwsc);
  // GEMM2 -> out [E,T,D]
  gemm_i8<false, I_, D_><<<dim3(D_ / 64, T_ / 128, E_), b, 0, stream>>>(
      aq, dwq, asc, dwsc, out);
}

// Round 2
// 806.186 us; speedup vs baseline: 1.3702x; 1.3702x over previous
//
#include <hip/hip_runtime.h>
#include <hip/hip_bf16.h>
#include <stdint.h>

// Problem constants (from setup_inputs): E=8, T=2048, D=2048, I=1024
constexpr int E_ = 8, T_ = 2048, D_ = 2048, I_ = 1024;
#define EPS_ 1e-6f
#define QMAX_ 127.0f

typedef int v4i __attribute__((ext_vector_type(4)));

// ---------------------------------------------------------------------------
// Stage-A column abs-max: partial[(e*16+rc)*cols + col] = max over 128 rows
// grid: (cols/256, 16, E), block 256
// ---------------------------------------------------------------------------
__global__ __launch_bounds__(256) void colmax_partial(
    const float* __restrict__ src, float* __restrict__ partial,
    int rows_pc, int cols) {
  int e = blockIdx.z, rc = blockIdx.y;
  int col = blockIdx.x * 256 + threadIdx.x;
  const float* p = src + (size_t)e * gridDim.y * rows_pc * cols +
                   (size_t)rc * rows_pc * cols + col;
  float m = 0.f;
  for (int r = 0; r < rows_pc; ++r) m = fmaxf(m, fabsf(p[(size_t)r * cols]));
  partial[((size_t)e * gridDim.y + rc) * cols + col] = m;
}

// ---------------------------------------------------------------------------
// s = max(sqrt(max(ax,EPS)/max(aw,EPS)), EPS), reducing 16 partials each
// grid: (cols/256, E)
// ---------------------------------------------------------------------------
__global__ __launch_bounds__(256) void compute_s(
    const float* __restrict__ px, const float* __restrict__ pw,
    float* __restrict__ s, int cols) {
  int e = blockIdx.y;
  int c = blockIdx.x * 256 + threadIdx.x;
  float ax = 0.f, aw = 0.f;
  for (int k = 0; k < 16; ++k) {
    ax = fmaxf(ax, px[((size_t)e * 16 + k) * cols + c]);
    aw = fmaxf(aw, pw[((size_t)e * 16 + k) * cols + c]);
  }
  float sv = sqrtf(fmaxf(ax, EPS_) / fmaxf(aw, EPS_));
  s[(size_t)e * cols + c] = fmaxf(sv, EPS_);
}

// ---------------------------------------------------------------------------
// Per-row quantize (float4 vectorized): v = src*s (MUL) or src/s;
// scale = max(rowmax|v|,EPS)/127; q = clip(rint(v/scale),-127,127)
// grid: (rows, E), block 256.
// ---------------------------------------------------------------------------
template <bool MUL, int COLS>
__global__ __launch_bounds__(256) void quant_rows(
    const float* __restrict__ src, const float* __restrict__ s,
    int8_t* __restrict__ q, float* __restrict__ rscale) {
  int e = blockIdx.y, r = blockIdx.x;
  const float4* row4 = (const float4*)(src + ((size_t)e * gridDim.x + r) * COLS);
  const float4* s4 = (const float4*)(s + (size_t)e * COLS);
  constexpr int NV = COLS / 1024;  // float4s per thread
  float4 vv[NV];
  float m = 0.f;
  for (int i = 0; i < NV; ++i) {
    int c = i * 256 + threadIdx.x;
    float4 rv = row4[c], sv = s4[c];
    float4 v;
    v.x = MUL ? rv.x * sv.x : rv.x / sv.x;
    v.y = MUL ? rv.y * sv.y : rv.y / sv.y;
    v.z = MUL ? rv.z * sv.z : rv.z / sv.z;
    v.w = MUL ? rv.w * sv.w : rv.w / sv.w;
    vv[i] = v;
    m = fmaxf(m, fmaxf(fmaxf(fabsf(v.x), fabsf(v.y)), fmaxf(fabsf(v.z), fabsf(v.w))));
  }
  __shared__ float red[256];
  red[threadIdx.x] = m;
  __syncthreads();
  for (int st = 128; st > 0; st >>= 1) {
    if (threadIdx.x < st) red[threadIdx.x] = fmaxf(red[threadIdx.x], red[threadIdx.x + st]);
    __syncthreads();
  }
  float scale = fmaxf(red[0], EPS_) / QMAX_;
  char4* qrow = (char4*)(q + ((size_t)e * gridDim.x + r) * COLS);
  for (int i = 0; i < NV; ++i) {
    int c = i * 256 + threadIdx.x;
    float4 v = vv[i];
    char4 o;
    o.x = (int8_t)fminf(fmaxf(rintf(v.x / scale), -QMAX_), QMAX_);
    o.y = (int8_t)fminf(fmaxf(rintf(v.y / scale), -QMAX_), QMAX_);
    o.z = (int8_t)fminf(fmaxf(rintf(v.z / scale), -QMAX_), QMAX_);
    o.w = (int8_t)fminf(fmaxf(rintf(v.w / scale), -QMAX_), QMAX_);
    qrow[c] = o;
  }
  if (threadIdx.x == 0) rscale[(size_t)e * gridDim.x + r] = scale;
}

// ---------------------------------------------------------------------------
// int8 GEMM: C[m,n] = sum_k A[m,k]*B[n,k], dequant by asc[m]*bsc[n].
// BM=128, BN=64, BK=64, mfma_i32_16x16x64_i8 (one MFMA spans full BK).
// A frag: 16 int8/lane (v4i), A[m=lane&15][k=quad*16+j]; C/D col=lane&15,
// row=quad*4+reg (dtype-independent mapping, verified round 1 via x32).
// LDS row stride 80B: bank = (row*20+quad*4)%32 -> 2-way max = free (m136).
// FUSE: also compute up-tile (B rows I_+n), SwiGLU epilogue -> a[T,I].
// block 256 (4 waves 2x2), grid (NOUT/64, T/128, E).
// ---------------------------------------------------------------------------
template <bool FUSE, int K, int NOUT>
__global__ __launch_bounds__(256) void gemm_i8(
    const int8_t* __restrict__ Aq, const int8_t* __restrict__ Bq,
    const float* __restrict__ asc, const float* __restrict__ bsc,
    float* __restrict__ outp) {
  constexpr int BM = 128, BN = 64, BK = 64, LST = 80;
  int e = blockIdx.z;
  int n0 = blockIdx.x * BN, m0 = blockIdx.y * BM;
  const int8_t* Ae = Aq + (size_t)e * T_ * K;
  const int8_t* Be = Bq + (size_t)e * 2048 * K;
  __shared__ int8_t sA[BM * LST];
  __shared__ int8_t sB[FUSE ? 2 : 1][BN * LST];
  int tid = threadIdx.x;
  int lane = tid & 63, wv = tid >> 6;
  int l16 = lane & 15, quad = lane >> 4;
  int wm = wv & 1, wn = wv >> 1;

  v4i accg[4][2], accu[4][2];
  for (int mt = 0; mt < 4; ++mt)
    for (int nt = 0; nt < 2; ++nt) {
      accg[mt][nt] = (v4i){0, 0, 0, 0};
      accu[mt][nt] = (v4i){0, 0, 0, 0};
    }

  int srow = tid >> 2, scol = (tid & 3) << 4;  // staging coords (64 rows/pass)
  for (int k0 = 0; k0 < K; k0 += BK) {
    // stage A tile (128x64 int8, 2 passes of 256x16B)
    for (int p = 0; p < 2; ++p) {
      int row = p * 64 + srow;
      *(int4*)(sA + row * LST + scol) =
          *(const int4*)(Ae + (size_t)(m0 + row) * K + k0 + scol);
    }
    // stage B tile(s) (64x64 int8 each, 1 pass)
    *(int4*)(&sB[0][srow * LST + scol]) =
        *(const int4*)(Be + (size_t)(n0 + srow) * K + k0 + scol);
    if (FUSE)
      *(int4*)(&sB[1][srow * LST + scol]) =
          *(const int4*)(Be + (size_t)(I_ + n0 + srow) * K + k0 + scol);
    __syncthreads();

    v4i af[4];
    for (int mt = 0; mt < 4; ++mt)
      af[mt] = *(const v4i*)(sA + (wm * 64 + mt * 16 + l16) * LST + quad * 16);
    v4i bf0[2], bf1[2];
    for (int nt = 0; nt < 2; ++nt) {
      int brow = wn * 32 + nt * 16 + l16;
      bf0[nt] = *(const v4i*)(&sB[0][brow * LST + quad * 16]);
      if (FUSE) bf1[nt] = *(const v4i*)(&sB[1][brow * LST + quad * 16]);
    }
    for (int mt = 0; mt < 4; ++mt)
      for (int nt = 0; nt < 2; ++nt) {
        accg[mt][nt] = __builtin_amdgcn_mfma_i32_16x16x64_i8(
            af[mt], bf0[nt], accg[mt][nt], 0, 0, 0);
        if (FUSE)
          accu[mt][nt] = __builtin_amdgcn_mfma_i32_16x16x64_i8(
              af[mt], bf1[nt], accu[mt][nt], 0, 0, 0);
      }
    __syncthreads();
  }

  const float* ascE = asc + (size_t)e * T_;
  const float* bscE = bsc + (size_t)e * 2048;
  for (int mt = 0; mt < 4; ++mt)
    for (int nt = 0; nt < 2; ++nt)
      for (int r2 = 0; r2 < 4; ++r2) {
        int grow = m0 + wm * 64 + mt * 16 + quad * 4 + r2;
        int gcol = n0 + wn * 32 + nt * 16 + l16;
        float as = ascE[grow];
        if (FUSE) {
          float g = (float)accg[mt][nt][r2] * as * bscE[gcol];
          float u = (float)accu[mt][nt][r2] * as * bscE[I_ + gcol];
          float sg = g / (1.0f + expf(-g));  // silu
          outp[(size_t)e * T_ * NOUT + (size_t)grow * NOUT + gcol] = sg * u;
        } else {
          outp[(size_t)e * T_ * NOUT + (size_t)grow * NOUT + gcol] =
              (float)accg[mt][nt][r2] * as * bscE[gcol];
        }
      }
}

// ---------------------------------------------------------------------------
extern "C" void kernel_launch(void* const* d_in, const int* in_sizes, int n_in,
                              void* d_out, int out_size, void* d_ws, size_t ws_size,
                              hipStream_t stream) {
  const float* x   = (const float*)d_in[0];   // [E,T,D]
  const float* guw = (const float*)d_in[1];   // [E,2I,D]
  const float* dw  = (const float*)d_in[2];   // [E,D,I]
  float* out = (float*)d_out;                 // [E,T,D] fp32

  char* ws = (char*)d_ws;
  size_t off = 0;
  auto alloc = [&](size_t bytes) { char* p = ws + off; off += bytes; return p; };
  int8_t* xq   = (int8_t*)alloc((size_t)E_ * T_ * D_);        // 32 MB
  int8_t* wq1  = (int8_t*)alloc((size_t)E_ * 2 * I_ * D_);    // 32 MB
  int8_t* aq   = (int8_t*)alloc((size_t)E_ * T_ * I_);        // 16 MB
  int8_t* dwq  = (int8_t*)alloc((size_t)E_ * D_ * I_);        // 16 MB
  float*  a    = (float*)alloc((size_t)E_ * T_ * I_ * 4);     // 64 MB
  float*  px   = (float*)alloc((size_t)E_ * 16 * D_ * 4);
  float*  pw   = (float*)alloc((size_t)E_ * 16 * D_ * 4);
  float*  pdw  = (float*)alloc((size_t)E_ * 16 * I_ * 4);
  float*  pa   = (float*)alloc((size_t)E_ * 16 * I_ * 4);
  float*  s1   = (float*)alloc((size_t)E_ * D_ * 4);
  float*  s2   = (float*)alloc((size_t)E_ * I_ * 4);
  float*  xsc  = (float*)alloc((size_t)E_ * T_ * 4);
  float*  wsc1 = (float*)alloc((size_t)E_ * 2 * I_ * 4);
  float*  asc  = (float*)alloc((size_t)E_ * T_ * 4);
  float*  dwsc = (float*)alloc((size_t)E_ * D_ * 4);

  dim3 b(256);
  // Linear 1 smoothing scales
  colmax_partial<<<dim3(D_ / 256, 16, E_), b, 0, stream>>>(x, px, 128, D_);
  colmax_partial<<<dim3(D_ / 256, 16, E_), b, 0, stream>>>(guw, pw, 128, D_);
  colmax_partial<<<dim3(I_ / 256, 16, E_), b, 0, stream>>>(dw, pdw, 128, I_);
  compute_s<<<dim3(D_ / 256, E_), b, 0, stream>>>(px, pw, s1, D_);
  // Quantize x (div by s) and guw (mul by s)
  quant_rows<false, D_><<<dim3(T_, E_), b, 0, stream>>>(x, s1, xq, xsc);
  quant_rows<true, D_><<<dim3(2 * I_, E_), b, 0, stream>>>(guw, s1, wq1, wsc1);
  // GEMM1 + SwiGLU -> a [E,T,I]
  gemm_i8<true, D_, I_><<<dim3(I_ / 64, T_ / 128, E_), b, 0, stream>>>(
      xq, wq1, xsc, wsc1, a);
  // Linear 2 smoothing scales
  colmax_partial<<<dim3(I_ / 256, 16, E_), b, 0, stream>>>(a, pa, 128, I_);
  compute_s<<<dim3(I_ / 256, E_), b, 0, stream>>>(pa, pdw, s2, I_);
  quant_rows<false, I_><<<dim3(T_, E_), b, 0, stream>>>(a, s2, aq, asc);
  quant_rows<true, I_><<<dim3(D_, E_), b, 0, stream>>>(dw, s2, dwq, dwsc);
  // GEMM2 -> out [E,T,D]
  gemm_i8<false, I_, D_><<<dim3(D_ / 64, T_ / 128, E_), b, 0, stream>>>(
      aq, dwq, asc, dwsc, out);
}